// Round 6
// baseline (1258.823 us; speedup 1.0000x reference)
//
#include <hip/hip_runtime.h>
#include <hip/hip_bf16.h>

#define NT    10
#define NN    2048   // n_neurons
#define CA3C  2048
#define SEQ   1024
#define SPARS 0.05f
#define LRC   0.01f

typedef float    f32x4 __attribute__((ext_vector_type(4)));

// ---------------- Phase A: hippo_input[s][n] = sum_t tok_spike*(1+0.5*pos_spike) ----
__global__ __launch_bounds__(256) void k_hippo(const int* __restrict__ tok,
        const float* __restrict__ sdr, const float* __restrict__ pos,
        float* __restrict__ hippo) {
    int s = blockIdx.x;
    int n = (blockIdx.y * 256 + threadIdx.x) * 4;
    const float* sp = sdr + (long)tok[s] * (NT * NN) + n;
    const float* pp = pos + (long)s * (NT * NN) + n;
    float a0 = 0.f, a1 = 0.f, a2 = 0.f, a3 = 0.f;
    #pragma unroll
    for (int t = 0; t < NT; ++t) {
        float4 sv = *(const float4*)(sp + t * NN);
        float4 pv = *(const float4*)(pp + t * NN);
        if (sv.x < SPARS) a0 += (pv.x < SPARS) ? 1.5f : 1.0f;
        if (sv.y < SPARS) a1 += (pv.y < SPARS) ? 1.5f : 1.0f;
        if (sv.z < SPARS) a2 += (pv.z < SPARS) ? 1.5f : 1.0f;
        if (sv.w < SPARS) a3 += (pv.w < SPARS) ? 1.5f : 1.0f;
    }
    *(float4*)(hippo + (long)s * NN + n) = make_float4(a0, a1, a2, a3);
}

// ---------------- Generic fp32 GEMM: C[m][n] = A[m]·B[n] (+ af[m]*Wadd[m][n]) -------
// A: M×K row-major, B: N×K row-major, C: M×N (ldc). M = gridDim.y*64, N = gridDim.x*64.
__global__ __launch_bounds__(256) void k_gemm(const float* __restrict__ A,
        const float* __restrict__ B, float* __restrict__ C, int K, int ldc,
        const float* __restrict__ Wadd, const float* __restrict__ af) {
    __shared__ float As[32][68];   // [k][m], padded
    __shared__ float Bs[32][68];   // [k][n]
    int tid = threadIdx.x;
    int tx = tid & 15, ty = tid >> 4;
    int m0 = blockIdx.y * 64, n0 = blockIdx.x * 64;
    int lr = tid >> 3;            // 0..31
    int lk = (tid & 7) * 4;       // 0..28
    float acc[4][4] = {};
    for (int k0 = 0; k0 < K; k0 += 32) {
        float4 a0 = *(const float4*)(A + (long)(m0 + lr) * K + k0 + lk);
        float4 a1 = *(const float4*)(A + (long)(m0 + lr + 32) * K + k0 + lk);
        float4 b0 = *(const float4*)(B + (long)(n0 + lr) * K + k0 + lk);
        float4 b1 = *(const float4*)(B + (long)(n0 + lr + 32) * K + k0 + lk);
        __syncthreads();
        As[lk + 0][lr] = a0.x; As[lk + 1][lr] = a0.y; As[lk + 2][lr] = a0.z; As[lk + 3][lr] = a0.w;
        As[lk + 0][lr + 32] = a1.x; As[lk + 1][lr + 32] = a1.y; As[lk + 2][lr + 32] = a1.z; As[lk + 3][lr + 32] = a1.w;
        Bs[lk + 0][lr] = b0.x; Bs[lk + 1][lr] = b0.y; Bs[lk + 2][lr] = b0.z; Bs[lk + 3][lr] = b0.w;
        Bs[lk + 0][lr + 32] = b1.x; Bs[lk + 1][lr + 32] = b1.y; Bs[lk + 2][lr + 32] = b1.z; Bs[lk + 3][lr + 32] = b1.w;
        __syncthreads();
        #pragma unroll
        for (int k = 0; k < 32; ++k) {
            float4 av = *(const float4*)&As[k][ty * 4];
            float4 bv = *(const float4*)&Bs[k][tx * 4];
            float aa[4] = {av.x, av.y, av.z, av.w};
            float bb[4] = {bv.x, bv.y, bv.z, bv.w};
            #pragma unroll
            for (int i = 0; i < 4; ++i)
                #pragma unroll
                for (int j = 0; j < 4; ++j)
                    acc[i][j] = fmaf(aa[i], bb[j], acc[i][j]);
        }
    }
    #pragma unroll
    for (int i = 0; i < 4; ++i) {
        float4 o = make_float4(acc[i][0], acc[i][1], acc[i][2], acc[i][3]);
        if (Wadd != nullptr) {
            float a = af[m0 + ty * 4 + i];
            float4 w = *(const float4*)(Wadd + (long)(m0 + ty * 4 + i) * ldc + n0 + tx * 4);
            o.x = fmaf(a, w.x, o.x); o.y = fmaf(a, w.y, o.y);
            o.z = fmaf(a, w.z, o.z); o.w = fmaf(a, w.w, o.w);
        }
        *(float4*)(C + (long)(m0 + ty * 4 + i) * ldc + n0 + tx * 4) = o;
    }
}

// ---------------- fp64 re-check of near-zero dots (sign safety) --------------------
__global__ __launch_bounds__(256) void k_fixup(const float* __restrict__ hippo,
        const float* __restrict__ w, float* __restrict__ dots) {
    long i = (long)blockIdx.x * 256 + threadIdx.x;
    float d = dots[i];
    if (fabsf(d) < 1e-3f) {
        int s = (int)(i / CA3C), c = (int)(i % CA3C);
        const float* hr = hippo + (long)s * NN;
        const float* wr = w + (long)c * NN;
        double acc = 0.0;
        for (int n = 0; n < NN; ++n) acc += (double)hr[n] * (double)wr[n];
        dots[i] = (acc > 0.0) ? 1.0f : -1.0f;   // only the sign is consumed
    }
}

// ---------------- pack: preT[w][s] bits, popf[s], dense Xf[s][n] -------------------
__global__ __launch_bounds__(64) void k_pack(const float* __restrict__ dots,
        unsigned* __restrict__ preT, float* __restrict__ popf, float* __restrict__ Xf) {
    int s = blockIdx.x;                        // 0..1023
    int w = threadIdx.x;                       // 0..63 -> word index
    const float* row = dots + (long)s * CA3C + w * 32;
    float* xrow = Xf + (long)s * CA3C + w * 32;
    unsigned m = 0;
    #pragma unroll
    for (int j4 = 0; j4 < 8; ++j4) {
        f32x4 v = *(const f32x4*)(row + j4 * 4);
        f32x4 xb;
        xb.x = v.x > 0.f ? 1.f : 0.f; xb.y = v.y > 0.f ? 1.f : 0.f;
        xb.z = v.z > 0.f ? 1.f : 0.f; xb.w = v.w > 0.f ? 1.f : 0.f;
        m |= (v.x > 0.f ? 1u : 0u) << (j4 * 4 + 0);
        m |= (v.y > 0.f ? 1u : 0u) << (j4 * 4 + 1);
        m |= (v.z > 0.f ? 1u : 0u) << (j4 * 4 + 2);
        m |= (v.w > 0.f ? 1u : 0u) << (j4 * 4 + 3);
        *(f32x4*)(xrow + j4 * 4) = xb;
    }
    preT[w * SEQ + s] = m;
    int pc = __popc(m);
    #pragma unroll
    for (int o = 1; o < 64; o <<= 1) pc += __shfl_xor(pc, o, 64);
    if (w == 0) popf[s] = (float)pc;
}

// ---------------- post bits per row: postT[r][32 words over steps 0..1022] ---------
__global__ __launch_bounds__(256) void k_packpost(const float* __restrict__ dots,
        unsigned* __restrict__ postT) {
    int r = blockIdx.x * 256 + threadIdx.x;    // 0..2047
    #pragma unroll 1
    for (int wi = 0; wi < 32; ++wi) {
        unsigned m = 0;
        int jmax = (wi == 31) ? 31 : 32;       // steps s = wi*32+j, s <= 1022
        for (int j = 0; j < jmax; ++j) {
            int s = wi * 32 + j;
            m |= (dots[(long)(s + 1) * CA3C + r] > 0.0f ? 1u : 0u) << j;
        }
        postT[r * 32 + wi] = m;
    }
}

// ---------------- transpose Xf[s][n] -> XfT[n][s] ----------------------------------
__global__ __launch_bounds__(256) void k_transpose(const float* __restrict__ Xf,
        float* __restrict__ XfT) {
    __shared__ float t[64][65];
    int s0 = blockIdx.x * 64, n0 = blockIdx.y * 64;
    int tx = threadIdx.x & 63, ty = threadIdx.x >> 6;
    #pragma unroll
    for (int ii = 0; ii < 16; ++ii) {
        int i = ty + ii * 4;
        t[i][tx] = Xf[(long)(s0 + i) * CA3C + n0 + tx];
    }
    __syncthreads();
    #pragma unroll
    for (int ii = 0; ii < 16; ++ii) {
        int i = ty + ii * 4;
        XfT[(long)(n0 + i) * SEQ + s0 + tx] = t[tx][i];
    }
}

// ---------------- Gram matrix G[i][j] = x_i . x_j via popcount ---------------------
__global__ __launch_bounds__(256) void k_gram(const unsigned* __restrict__ preT,
        float* __restrict__ G) {
    int i = blockIdx.x;
    int t = threadIdx.x;
    int a0 = 0, a1 = 0, a2 = 0, a3 = 0;
    #pragma unroll 8
    for (int w = 0; w < 64; ++w) {
        unsigned ri = preT[w * SEQ + i];       // uniform -> broadcast
        const unsigned* pr = preT + w * SEQ;
        a0 += __popc(ri & pr[t]);
        a1 += __popc(ri & pr[t + 256]);
        a2 += __popc(ri & pr[t + 512]);
        a3 += __popc(ri & pr[t + 768]);
    }
    long base = (long)i * SEQ;
    G[base + t] = (float)a0;       G[base + t + 256] = (float)a1;
    G[base + t + 512] = (float)a2; G[base + t + 768] = (float)a3;
}

// ---------------- DPP-based full-wave (64 lane) sum; broadcast via lane 63 ---------
__device__ __forceinline__ float wave_sum64(float x) {
    #define DPPADD(ctrl, rmask) \
        x += __int_as_float(__builtin_amdgcn_update_dpp(0, __float_as_int(x), ctrl, rmask, 0xF, true))
    DPPADD(0xB1, 0xF);    // quad_perm [1,0,3,2]
    DPPADD(0x4E, 0xF);    // quad_perm [2,3,0,1]
    DPPADD(0x141, 0xF);   // row_half_mirror
    DPPADD(0x140, 0xF);   // row_mirror
    DPPADD(0x142, 0xA);   // row_bcast15
    DPPADD(0x143, 0xC);   // row_bcast31
    #undef DPPADD
    return __int_as_float(__builtin_amdgcn_readlane(__float_as_int(x), 63));
}

// ---------------- Phase D (Gram form): scalar alpha/nu recurrence per row ----------
// dot_s = s0*B0[r][s] + sum_{s'<s active} c_{s'} * G[s'][s]  -- no V state at all.
// c history lives in LDS (ctab, 4 KB/wave); per-block rescale event keeps inv_alpha
// in fp32 range (nu is scale-invariant). Final W = (alpha*s0)*W0 + sum c*x via GEMM.
__global__ __launch_bounds__(256) void k_scan2(const float* __restrict__ W0,
        const float* __restrict__ B0, const float* __restrict__ G,
        const unsigned* __restrict__ postT, const float* __restrict__ popf,
        float* __restrict__ coef, float* __restrict__ alphaf) {
    __shared__ float Gd[64][64];     // diag block of G
    __shared__ float ctab[4][1024];  // per-wave c history
    int wid = threadIdx.x >> 6, lane = threadIdx.x & 63;
    int r = blockIdx.x * 4 + wid;
    #pragma unroll
    for (int kk = 0; kk < 16; ++kk) ctab[wid][kk * 64 + lane] = 0.f;
    // initial nu = ||W0_r||^2
    const float* wr = W0 + (long)r * NN + lane * 32;
    f32x4 q0 = *(const f32x4*)(wr +  0), q1 = *(const f32x4*)(wr +  4);
    f32x4 q2 = *(const f32x4*)(wr +  8), q3 = *(const f32x4*)(wr + 12);
    f32x4 q4 = *(const f32x4*)(wr + 16), q5 = *(const f32x4*)(wr + 20);
    f32x4 q6 = *(const f32x4*)(wr + 24), q7 = *(const f32x4*)(wr + 28);
    f32x4 pp = q0*q0 + q1*q1 + q2*q2 + q3*q3 + q4*q4 + q5*q5 + q6*q6 + q7*q7;
    float nu = wave_sum64((pp.x + pp.y) + (pp.z + pp.w));
    float alpha = 1.f, inv_alpha = 1.f;
    { float t = fmaxf(nu, 1.f); alpha *= rsqrtf(t); inv_alpha *= sqrtf(t); nu = fminf(nu, 1.f); }
    float s0 = 1.f;

    for (int b = 0; b < 16; ++b) {
        __syncthreads();
        {   // cooperative stage of G diag block [64b..64b+63]^2
            int gi = threadIdx.x >> 2, gj = (threadIdx.x & 3) * 16;
            const float* gs = G + (long)(b * 64 + gi) * SEQ + b * 64 + gj;
            *(f32x4*)&Gd[gi][gj +  0] = *(const f32x4*)(gs +  0);
            *(f32x4*)&Gd[gi][gj +  4] = *(const f32x4*)(gs +  4);
            *(f32x4*)&Gd[gi][gj +  8] = *(const f32x4*)(gs +  8);
            *(f32x4*)&Gd[gi][gj + 12] = *(const f32x4*)(gs + 12);
        }
        __syncthreads();
        float myB0  = B0[(long)r * SEQ + b * 64 + lane];
        float mypop = popf[b * 64 + lane];
        unsigned long long pm;
        {   unsigned lo = postT[r * 32 + 2 * b], hi = postT[r * 32 + 2 * b + 1];
            pm = ((unsigned long long)(unsigned)__builtin_amdgcn_readfirstlane((int)hi) << 32)
               |  (unsigned long long)(unsigned)__builtin_amdgcn_readfirstlane((int)lo);
        }
        // inter-block: lane j streams its G row (symmetry: G[64b+j][s'] == G[s'][64b+j])
        f32x4 ibv = {0.f, 0.f, 0.f, 0.f};
        const float* grow = G + (long)(b * 64 + lane) * SEQ;
        #pragma unroll 4
        for (int l4 = 0; l4 < b * 16; ++l4) {
            f32x4 cq = *(const f32x4*)&ctab[wid][l4 * 4];    // uniform addr -> broadcast
            f32x4 gq = *(const f32x4*)(grow + l4 * 4);
            ibv += cq * gq;
        }
        float acc = fmaf(s0, myB0, (ibv.x + ibv.y) + (ibv.z + ibv.w));
        float cj = 0.f;
        #pragma unroll
        for (int j = 0; j < 64; ++j) {
            if ((pm >> j) & 1ull) {          // wave-uniform branch
                float dot = __int_as_float(__builtin_amdgcn_readlane(__float_as_int(acc), j));
                float pj  = __int_as_float(__builtin_amdgcn_readlane(__float_as_int(mypop), j));
                float c = LRC * inv_alpha;
                nu = fmaf(2.f * LRC, alpha * dot, fmaf(LRC * LRC, pj, nu));
                float t = fmaxf(nu, 1.f);
                alpha *= rsqrtf(t); inv_alpha *= sqrtf(t); nu = fminf(nu, 1.f);
                acc = fmaf(c, Gd[j][lane], acc);     // fold step j into future steps
                cj = (lane == j) ? c : cj;
            }
        }
        ctab[wid][b * 64 + lane] = cj;
        if (inv_alpha > 1e10f) {             // rescale event: fold alpha into V-space
            #pragma unroll 1
            for (int kk = 0; kk <= b; ++kk) ctab[wid][kk * 64 + lane] *= alpha;
            s0 *= alpha; alpha = 1.f; inv_alpha = 1.f;
        }
    }
    if (lane == 0) alphaf[r] = alpha * s0;
    #pragma unroll
    for (int kk = 0; kk < 16; ++kk)
        coef[(long)r * SEQ + kk * 64 + lane] = alpha * ctab[wid][kk * 64 + lane];
}

extern "C" void kernel_launch(void* const* d_in, const int* in_sizes, int n_in,
                              void* d_out, int out_size, void* d_ws, size_t ws_size,
                              hipStream_t stream) {
    const int*   tok     = (const int*)d_in[0];
    const float* sdr     = (const float*)d_in[1];
    const float* pos     = (const float*)d_in[2];
    const float* w_hippo = (const float*)d_in[3];
    const float* assoc   = (const float*)d_in[4];
    float* out = (float*)d_out;

    char* ws = (char*)d_ws;
    float*    hippoG = (float*)(ws);                       // hippo 8 MB, later G (4 MB)
    float*    dotsB0 = (float*)(ws + (8l << 20));          // dots 8 MB, later B0 (8 MB)
    float*    Xf     = (float*)(ws + (16l << 20));         // 8 MB
    float*    XfT    = (float*)(ws + (24l << 20));         // 8 MB
    float*    coef   = (float*)(ws + (32l << 20));         // 8 MB
    unsigned* preT   = (unsigned*)(ws + (40l << 20));      // 256 KB
    unsigned* postT  = (unsigned*)(ws + (40l << 20) + 262144);        // 256 KB
    float*    popf   = (float*)(ws + (40l << 20) + 524288);           // 4 KB
    float*    alphaf = (float*)(ws + (40l << 20) + 532480);           // 8 KB

    k_hippo    <<<dim3(SEQ, 2),  256, 0, stream>>>(tok, sdr, pos, hippoG);
    k_gemm     <<<dim3(32, 16),  256, 0, stream>>>(hippoG, w_hippo, dotsB0, NN, CA3C, nullptr, nullptr);
    k_fixup    <<<dim3(8192),    256, 0, stream>>>(hippoG, w_hippo, dotsB0);
    k_pack     <<<dim3(SEQ),      64, 0, stream>>>(dotsB0, preT, popf, Xf);
    k_packpost <<<dim3(8),       256, 0, stream>>>(dotsB0, postT);
    k_transpose<<<dim3(16, 32),  256, 0, stream>>>(Xf, XfT);
    k_gram     <<<dim3(SEQ),     256, 0, stream>>>(preT, hippoG);               // G overwrites hippo
    k_gemm     <<<dim3(16, 32),  256, 0, stream>>>(assoc, Xf, dotsB0, NN, SEQ, nullptr, nullptr); // B0
    k_scan2    <<<dim3(512),     256, 0, stream>>>(assoc, dotsB0, hippoG, postT, popf, coef, alphaf);
    k_gemm     <<<dim3(32, 32),  256, 0, stream>>>(coef, XfT, out, SEQ, CA3C, assoc, alphaf);     // W
}

// Round 7
// 1195.990 us; speedup vs baseline: 1.0525x; 1.0525x over previous
//
#include <hip/hip_runtime.h>
#include <hip/hip_bf16.h>

#define NT    10
#define NN    2048   // n_neurons
#define CA3C  2048
#define SEQ   1024
#define SPARS 0.05f
#define LRC   0.01f

typedef float    f32x4 __attribute__((ext_vector_type(4)));

// ---------------- Phase A: hippo_input[s][n] = sum_t tok_spike*(1+0.5*pos_spike) ----
__global__ __launch_bounds__(256) void k_hippo(const int* __restrict__ tok,
        const float* __restrict__ sdr, const float* __restrict__ pos,
        float* __restrict__ hippo) {
    int s = blockIdx.x;
    int n = (blockIdx.y * 256 + threadIdx.x) * 4;
    const float* sp = sdr + (long)tok[s] * (NT * NN) + n;
    const float* pp = pos + (long)s * (NT * NN) + n;
    float a0 = 0.f, a1 = 0.f, a2 = 0.f, a3 = 0.f;
    #pragma unroll
    for (int t = 0; t < NT; ++t) {
        float4 sv = *(const float4*)(sp + t * NN);
        float4 pv = *(const float4*)(pp + t * NN);
        if (sv.x < SPARS) a0 += (pv.x < SPARS) ? 1.5f : 1.0f;
        if (sv.y < SPARS) a1 += (pv.y < SPARS) ? 1.5f : 1.0f;
        if (sv.z < SPARS) a2 += (pv.z < SPARS) ? 1.5f : 1.0f;
        if (sv.w < SPARS) a3 += (pv.w < SPARS) ? 1.5f : 1.0f;
    }
    *(float4*)(hippo + (long)s * NN + n) = make_float4(a0, a1, a2, a3);
}

// ---------------- Generic fp32 GEMM: C[m][n] = A[m]·B[n] (+ af[m]*Wadd[m][n]) -------
// A: M×K row-major, B: N×K row-major, C: M×N (ldc). M = gridDim.y*64, N = gridDim.x*64.
__global__ __launch_bounds__(256) void k_gemm(const float* __restrict__ A,
        const float* __restrict__ B, float* __restrict__ C, int K, int ldc,
        const float* __restrict__ Wadd, const float* __restrict__ af) {
    __shared__ float As[32][68];   // [k][m], padded
    __shared__ float Bs[32][68];   // [k][n]
    int tid = threadIdx.x;
    int tx = tid & 15, ty = tid >> 4;
    int m0 = blockIdx.y * 64, n0 = blockIdx.x * 64;
    int lr = tid >> 3;            // 0..31
    int lk = (tid & 7) * 4;       // 0..28
    float acc[4][4] = {};
    for (int k0 = 0; k0 < K; k0 += 32) {
        float4 a0 = *(const float4*)(A + (long)(m0 + lr) * K + k0 + lk);
        float4 a1 = *(const float4*)(A + (long)(m0 + lr + 32) * K + k0 + lk);
        float4 b0 = *(const float4*)(B + (long)(n0 + lr) * K + k0 + lk);
        float4 b1 = *(const float4*)(B + (long)(n0 + lr + 32) * K + k0 + lk);
        __syncthreads();
        As[lk + 0][lr] = a0.x; As[lk + 1][lr] = a0.y; As[lk + 2][lr] = a0.z; As[lk + 3][lr] = a0.w;
        As[lk + 0][lr + 32] = a1.x; As[lk + 1][lr + 32] = a1.y; As[lk + 2][lr + 32] = a1.z; As[lk + 3][lr + 32] = a1.w;
        Bs[lk + 0][lr] = b0.x; Bs[lk + 1][lr] = b0.y; Bs[lk + 2][lr] = b0.z; Bs[lk + 3][lr] = b0.w;
        Bs[lk + 0][lr + 32] = b1.x; Bs[lk + 1][lr + 32] = b1.y; Bs[lk + 2][lr + 32] = b1.z; Bs[lk + 3][lr + 32] = b1.w;
        __syncthreads();
        #pragma unroll
        for (int k = 0; k < 32; ++k) {
            float4 av = *(const float4*)&As[k][ty * 4];
            float4 bv = *(const float4*)&Bs[k][tx * 4];
            float aa[4] = {av.x, av.y, av.z, av.w};
            float bb[4] = {bv.x, bv.y, bv.z, bv.w};
            #pragma unroll
            for (int i = 0; i < 4; ++i)
                #pragma unroll
                for (int j = 0; j < 4; ++j)
                    acc[i][j] = fmaf(aa[i], bb[j], acc[i][j]);
        }
    }
    #pragma unroll
    for (int i = 0; i < 4; ++i) {
        float4 o = make_float4(acc[i][0], acc[i][1], acc[i][2], acc[i][3]);
        if (Wadd != nullptr) {
            float a = af[m0 + ty * 4 + i];
            float4 w = *(const float4*)(Wadd + (long)(m0 + ty * 4 + i) * ldc + n0 + tx * 4);
            o.x = fmaf(a, w.x, o.x); o.y = fmaf(a, w.y, o.y);
            o.z = fmaf(a, w.z, o.z); o.w = fmaf(a, w.w, o.w);
        }
        *(float4*)(C + (long)(m0 + ty * 4 + i) * ldc + n0 + tx * 4) = o;
    }
}

// ---------------- fp64 re-check of near-zero dots (sign safety) --------------------
__global__ __launch_bounds__(256) void k_fixup(const float* __restrict__ hippo,
        const float* __restrict__ w, float* __restrict__ dots) {
    long i = (long)blockIdx.x * 256 + threadIdx.x;
    float d = dots[i];
    if (fabsf(d) < 1e-3f) {
        int s = (int)(i / CA3C), c = (int)(i % CA3C);
        const float* hr = hippo + (long)s * NN;
        const float* wr = w + (long)c * NN;
        double acc = 0.0;
        for (int n = 0; n < NN; ++n) acc += (double)hr[n] * (double)wr[n];
        dots[i] = (acc > 0.0) ? 1.0f : -1.0f;   // only the sign is consumed
    }
}

// ---------------- pack: preT[w][s] bits, popf[s], dense Xf[s][n] -------------------
__global__ __launch_bounds__(64) void k_pack(const float* __restrict__ dots,
        unsigned* __restrict__ preT, float* __restrict__ popf, float* __restrict__ Xf) {
    int s = blockIdx.x;                        // 0..1023
    int w = threadIdx.x;                       // 0..63 -> word index
    const float* row = dots + (long)s * CA3C + w * 32;
    float* xrow = Xf + (long)s * CA3C + w * 32;
    unsigned m = 0;
    #pragma unroll
    for (int j4 = 0; j4 < 8; ++j4) {
        f32x4 v = *(const f32x4*)(row + j4 * 4);
        f32x4 xb;
        xb.x = v.x > 0.f ? 1.f : 0.f; xb.y = v.y > 0.f ? 1.f : 0.f;
        xb.z = v.z > 0.f ? 1.f : 0.f; xb.w = v.w > 0.f ? 1.f : 0.f;
        m |= (v.x > 0.f ? 1u : 0u) << (j4 * 4 + 0);
        m |= (v.y > 0.f ? 1u : 0u) << (j4 * 4 + 1);
        m |= (v.z > 0.f ? 1u : 0u) << (j4 * 4 + 2);
        m |= (v.w > 0.f ? 1u : 0u) << (j4 * 4 + 3);
        *(f32x4*)(xrow + j4 * 4) = xb;
    }
    preT[w * SEQ + s] = m;
    int pc = __popc(m);
    #pragma unroll
    for (int o = 1; o < 64; o <<= 1) pc += __shfl_xor(pc, o, 64);
    if (w == 0) popf[s] = (float)pc;
}

// ---------------- post bits per row: postT[r][32 words over steps 0..1022] ---------
__global__ __launch_bounds__(256) void k_packpost(const float* __restrict__ dots,
        unsigned* __restrict__ postT) {
    int r = blockIdx.x * 256 + threadIdx.x;    // 0..2047
    #pragma unroll 1
    for (int wi = 0; wi < 32; ++wi) {
        unsigned m = 0;
        int jmax = (wi == 31) ? 31 : 32;       // steps s = wi*32+j, s <= 1022
        for (int j = 0; j < jmax; ++j) {
            int s = wi * 32 + j;
            m |= (dots[(long)(s + 1) * CA3C + r] > 0.0f ? 1u : 0u) << j;
        }
        postT[r * 32 + wi] = m;
    }
}

// ---------------- transpose Xf[s][n] -> XfT[n][s] ----------------------------------
__global__ __launch_bounds__(256) void k_transpose(const float* __restrict__ Xf,
        float* __restrict__ XfT) {
    __shared__ float t[64][65];
    int s0 = blockIdx.x * 64, n0 = blockIdx.y * 64;
    int tx = threadIdx.x & 63, ty = threadIdx.x >> 6;
    #pragma unroll
    for (int ii = 0; ii < 16; ++ii) {
        int i = ty + ii * 4;
        t[i][tx] = Xf[(long)(s0 + i) * CA3C + n0 + tx];
    }
    __syncthreads();
    #pragma unroll
    for (int ii = 0; ii < 16; ++ii) {
        int i = ty + ii * 4;
        XfT[(long)(n0 + i) * SEQ + s0 + tx] = t[tx][i];
    }
}

// ---------------- Gram matrix G[i][j] = x_i . x_j via popcount ---------------------
__global__ __launch_bounds__(256) void k_gram(const unsigned* __restrict__ preT,
        float* __restrict__ G) {
    int i = blockIdx.x;
    int t = threadIdx.x;
    int a0 = 0, a1 = 0, a2 = 0, a3 = 0;
    #pragma unroll 8
    for (int w = 0; w < 64; ++w) {
        unsigned ri = preT[w * SEQ + i];       // uniform -> broadcast
        const unsigned* pr = preT + w * SEQ;
        a0 += __popc(ri & pr[t]);
        a1 += __popc(ri & pr[t + 256]);
        a2 += __popc(ri & pr[t + 512]);
        a3 += __popc(ri & pr[t + 768]);
    }
    long base = (long)i * SEQ;
    G[base + t] = (float)a0;       G[base + t + 256] = (float)a1;
    G[base + t + 512] = (float)a2; G[base + t + 768] = (float)a3;
}

// ---------------- DPP-based full-wave (64 lane) sum; broadcast via lane 63 ---------
__device__ __forceinline__ float wave_sum64(float x) {
    #define DPPADD(ctrl, rmask) \
        x += __int_as_float(__builtin_amdgcn_update_dpp(0, __float_as_int(x), ctrl, rmask, 0xF, true))
    DPPADD(0xB1, 0xF);    // quad_perm [1,0,3,2]
    DPPADD(0x4E, 0xF);    // quad_perm [2,3,0,1]
    DPPADD(0x141, 0xF);   // row_half_mirror
    DPPADD(0x140, 0xF);   // row_mirror
    DPPADD(0x142, 0xA);   // row_bcast15
    DPPADD(0x143, 0xC);   // row_bcast31
    #undef DPPADD
    return __int_as_float(__builtin_amdgcn_readlane(__float_as_int(x), 63));
}

// ---------------- Phase D (Gram form): scalar alpha/nu recurrence per row ----------
// dot_s = s0*B0[r][s] + sum_{s'<s active} c_{s'} * G[s'][s]  -- no V state.
// R6 fix: inter-block stream now reads G in COALESCED orientation. By symmetry the
// needed value is G[s'][b*64+lane]: loop over s' (uniform), lane indexes the column
// -> 64 consecutive floats (4 cache lines) per instruction instead of 64 lines
// (R5 form had 4KB lane stride -> TA line-request bound, 514us, VALUBusy 14%).
// Accumulators ib0..3 group s' by (s' mod 4) == bit-identical sum order vs R5.
__global__ __launch_bounds__(256) void k_scan2(const float* __restrict__ W0,
        const float* __restrict__ B0, const float* __restrict__ G,
        const unsigned* __restrict__ postT, const float* __restrict__ popf,
        float* __restrict__ coef, float* __restrict__ alphaf) {
    __shared__ float Gd[64][68];     // diag block of G (pad 68: kills 16-way staging conflicts)
    __shared__ float ctab[4][1024];  // per-wave c history
    int wid = threadIdx.x >> 6, lane = threadIdx.x & 63;
    int r = blockIdx.x * 4 + wid;
    #pragma unroll
    for (int kk = 0; kk < 16; ++kk) ctab[wid][kk * 64 + lane] = 0.f;
    // initial nu = ||W0_r||^2
    const float* wr = W0 + (long)r * NN + lane * 32;
    f32x4 q0 = *(const f32x4*)(wr +  0), q1 = *(const f32x4*)(wr +  4);
    f32x4 q2 = *(const f32x4*)(wr +  8), q3 = *(const f32x4*)(wr + 12);
    f32x4 q4 = *(const f32x4*)(wr + 16), q5 = *(const f32x4*)(wr + 20);
    f32x4 q6 = *(const f32x4*)(wr + 24), q7 = *(const f32x4*)(wr + 28);
    f32x4 pp = q0*q0 + q1*q1 + q2*q2 + q3*q3 + q4*q4 + q5*q5 + q6*q6 + q7*q7;
    float nu = wave_sum64((pp.x + pp.y) + (pp.z + pp.w));
    float alpha = 1.f, inv_alpha = 1.f;
    { float t = fmaxf(nu, 1.f); alpha *= rsqrtf(t); inv_alpha *= sqrtf(t); nu = fminf(nu, 1.f); }
    float s0 = 1.f;

    for (int b = 0; b < 16; ++b) {
        __syncthreads();
        {   // cooperative stage of G diag block [64b..64b+63]^2
            int gi = threadIdx.x >> 2, gj = (threadIdx.x & 3) * 16;
            const float* gs = G + (long)(b * 64 + gi) * SEQ + b * 64 + gj;
            *(f32x4*)&Gd[gi][gj +  0] = *(const f32x4*)(gs +  0);
            *(f32x4*)&Gd[gi][gj +  4] = *(const f32x4*)(gs +  4);
            *(f32x4*)&Gd[gi][gj +  8] = *(const f32x4*)(gs +  8);
            *(f32x4*)&Gd[gi][gj + 12] = *(const f32x4*)(gs + 12);
        }
        __syncthreads();
        float myB0  = B0[(long)r * SEQ + b * 64 + lane];
        float mypop = popf[b * 64 + lane];
        unsigned long long pm;
        {   unsigned lo = postT[r * 32 + 2 * b], hi = postT[r * 32 + 2 * b + 1];
            pm = ((unsigned long long)(unsigned)__builtin_amdgcn_readfirstlane((int)hi) << 32)
               |  (unsigned long long)(unsigned)__builtin_amdgcn_readfirstlane((int)lo);
        }
        // inter-block: coalesced — lane reads column (b*64+lane) of rows s' = 0..b*64-1
        float ib0 = 0.f, ib1 = 0.f, ib2 = 0.f, ib3 = 0.f;
        const float* gcol = G + (long)b * 64 + lane;
        #pragma unroll 2
        for (int sp = 0; sp < b * 64; sp += 4) {
            f32x4 cq = *(const f32x4*)&ctab[wid][sp];        // uniform -> broadcast
            ib0 = fmaf(cq.x, gcol[(long)(sp + 0) * SEQ], ib0);
            ib1 = fmaf(cq.y, gcol[(long)(sp + 1) * SEQ], ib1);
            ib2 = fmaf(cq.z, gcol[(long)(sp + 2) * SEQ], ib2);
            ib3 = fmaf(cq.w, gcol[(long)(sp + 3) * SEQ], ib3);
        }
        float acc = fmaf(s0, myB0, (ib0 + ib1) + (ib2 + ib3));
        float cj = 0.f;
        #pragma unroll
        for (int j = 0; j < 64; ++j) {
            if ((pm >> j) & 1ull) {          // wave-uniform branch
                float dot = __int_as_float(__builtin_amdgcn_readlane(__float_as_int(acc), j));
                float pj  = __int_as_float(__builtin_amdgcn_readlane(__float_as_int(mypop), j));
                float c = LRC * inv_alpha;
                nu = fmaf(2.f * LRC, alpha * dot, fmaf(LRC * LRC, pj, nu));
                float t = fmaxf(nu, 1.f);
                alpha *= rsqrtf(t); inv_alpha *= sqrtf(t); nu = fminf(nu, 1.f);
                acc = fmaf(c, Gd[j][lane], acc);     // fold step j into future steps
                cj = (lane == j) ? c : cj;
            }
        }
        ctab[wid][b * 64 + lane] = cj;
        if (inv_alpha > 1e10f) {             // rescale event: fold alpha into V-space
            #pragma unroll 1
            for (int kk = 0; kk <= b; ++kk) ctab[wid][kk * 64 + lane] *= alpha;
            s0 *= alpha; alpha = 1.f; inv_alpha = 1.f;
        }
    }
    if (lane == 0) alphaf[r] = alpha * s0;
    #pragma unroll
    for (int kk = 0; kk < 16; ++kk)
        coef[(long)r * SEQ + kk * 64 + lane] = alpha * ctab[wid][kk * 64 + lane];
}

extern "C" void kernel_launch(void* const* d_in, const int* in_sizes, int n_in,
                              void* d_out, int out_size, void* d_ws, size_t ws_size,
                              hipStream_t stream) {
    const int*   tok     = (const int*)d_in[0];
    const float* sdr     = (const float*)d_in[1];
    const float* pos     = (const float*)d_in[2];
    const float* w_hippo = (const float*)d_in[3];
    const float* assoc   = (const float*)d_in[4];
    float* out = (float*)d_out;

    char* ws = (char*)d_ws;
    float*    hippoG = (float*)(ws);                       // hippo 8 MB, later G (4 MB)
    float*    dotsB0 = (float*)(ws + (8l << 20));          // dots 8 MB, later B0 (8 MB)
    float*    Xf     = (float*)(ws + (16l << 20));         // 8 MB
    float*    XfT    = (float*)(ws + (24l << 20));         // 8 MB
    float*    coef   = (float*)(ws + (32l << 20));         // 8 MB
    unsigned* preT   = (unsigned*)(ws + (40l << 20));      // 256 KB
    unsigned* postT  = (unsigned*)(ws + (40l << 20) + 262144);        // 256 KB
    float*    popf   = (float*)(ws + (40l << 20) + 524288);           // 4 KB
    float*    alphaf = (float*)(ws + (40l << 20) + 532480);           // 8 KB

    k_hippo    <<<dim3(SEQ, 2),  256, 0, stream>>>(tok, sdr, pos, hippoG);
    k_gemm     <<<dim3(32, 16),  256, 0, stream>>>(hippoG, w_hippo, dotsB0, NN, CA3C, nullptr, nullptr);
    k_fixup    <<<dim3(8192),    256, 0, stream>>>(hippoG, w_hippo, dotsB0);
    k_pack     <<<dim3(SEQ),      64, 0, stream>>>(dotsB0, preT, popf, Xf);
    k_packpost <<<dim3(8),       256, 0, stream>>>(dotsB0, postT);
    k_transpose<<<dim3(16, 32),  256, 0, stream>>>(Xf, XfT);
    k_gram     <<<dim3(SEQ),     256, 0, stream>>>(preT, hippoG);               // G overwrites hippo
    k_gemm     <<<dim3(16, 32),  256, 0, stream>>>(assoc, Xf, dotsB0, NN, SEQ, nullptr, nullptr); // B0
    k_scan2    <<<dim3(512),     256, 0, stream>>>(assoc, dotsB0, hippoG, postT, popf, coef, alphaf);
    k_gemm     <<<dim3(32, 32),  256, 0, stream>>>(coef, XfT, out, SEQ, CA3C, assoc, alphaf);     // W
}

// Round 8
// 1125.299 us; speedup vs baseline: 1.1187x; 1.0628x over previous
//
#include <hip/hip_runtime.h>
#include <hip/hip_bf16.h>

#define NT    10
#define NN    2048   // n_neurons
#define CA3C  2048
#define SEQ   1024
#define SPARS 0.05f
#define LRC   0.01f

typedef float          f32x4  __attribute__((ext_vector_type(4)));
typedef short          bf16x8 __attribute__((ext_vector_type(8)));
typedef unsigned short u16x4  __attribute__((ext_vector_type(4)));
typedef unsigned short u16x8  __attribute__((ext_vector_type(8)));

__device__ __forceinline__ unsigned short f2bf(float f) {   // RNE float->bf16 bits
    unsigned u = __float_as_uint(f);
    u += 0x7FFFu + ((u >> 16) & 1u);
    return (unsigned short)(u >> 16);
}
__device__ __forceinline__ float bf2f(unsigned short h) {
    return __uint_as_float(((unsigned)h) << 16);
}

// ---------------- Phase A: hippo_input (exact in bf16: values k*0.5, k<=30) --------
__global__ __launch_bounds__(256) void k_hippo(const int* __restrict__ tok,
        const float* __restrict__ sdr, const float* __restrict__ pos,
        unsigned short* __restrict__ Hh) {
    int s = blockIdx.x;
    int n = (blockIdx.y * 256 + threadIdx.x) * 4;
    const float* sp = sdr + (long)tok[s] * (NT * NN) + n;
    const float* pp = pos + (long)s * (NT * NN) + n;
    float a0 = 0.f, a1 = 0.f, a2 = 0.f, a3 = 0.f;
    #pragma unroll
    for (int t = 0; t < NT; ++t) {
        float4 sv = *(const float4*)(sp + t * NN);
        float4 pv = *(const float4*)(pp + t * NN);
        if (sv.x < SPARS) a0 += (pv.x < SPARS) ? 1.5f : 1.0f;
        if (sv.y < SPARS) a1 += (pv.y < SPARS) ? 1.5f : 1.0f;
        if (sv.z < SPARS) a2 += (pv.z < SPARS) ? 1.5f : 1.0f;
        if (sv.w < SPARS) a3 += (pv.w < SPARS) ? 1.5f : 1.0f;
    }
    u16x4 o = { f2bf(a0), f2bf(a1), f2bf(a2), f2bf(a3) };
    *(u16x4*)(Hh + (long)s * NN + n) = o;
}

// ---------------- split fp32 -> bf16 hi (+ optional lo residual) -------------------
__global__ __launch_bounds__(256) void k_split(const float* __restrict__ src,
        unsigned short* __restrict__ hi, unsigned short* __restrict__ lo) {
    long i = ((long)blockIdx.x * 256 + threadIdx.x) * 8;
    f32x4 x0 = *(const f32x4*)(src + i);
    f32x4 x1 = *(const f32x4*)(src + i + 4);
    float xs[8] = {x0.x, x0.y, x0.z, x0.w, x1.x, x1.y, x1.z, x1.w};
    u16x8 h, l;
    #pragma unroll
    for (int j = 0; j < 8; ++j) {
        unsigned short hb = f2bf(xs[j]);
        h[j] = hb;
        l[j] = f2bf(xs[j] - bf2f(hb));
    }
    *(u16x8*)(hi + i) = h;
    if (lo) *(u16x8*)(lo + i) = l;
}

// ---------------- MFMA GEMM: C[M][N] = A @ B^T, bf16 inputs, fp32 accum ------------
// A:[M][K] bf16, B:[N][K] bf16 (row-major, K contiguous). 128x128 tile, BK=32,
// 4 waves x (64x64). SPLIT_A: + A1@B ; SPLIT_B: + A@B1 (hi/lo split passes).
// LDS tile layout [kb=4][row=128][8] bf16 -> conflict-free b128 frag reads; staged
// via global_load_lds width 16 (linear dest = wave base + lane*16).
#define SPLIT_NONE 0
#define SPLIT_A    1
#define SPLIT_B    2

template<int MODE>
__global__ __launch_bounds__(256, 1) void k_mgemm(
        const unsigned short* __restrict__ A0, const unsigned short* __restrict__ A1,
        const unsigned short* __restrict__ Bh, const unsigned short* __restrict__ B1,
        float* __restrict__ C, int M, int N, int K,
        const float* __restrict__ Wadd, const float* __restrict__ af) {
    __shared__ unsigned short LA[4096], LB[4096], LX[4096];   // 8 KB each
    int tid = threadIdx.x, wid = tid >> 6, l = tid & 63;
    int m0 = blockIdx.y * 128, n0 = blockIdx.x * 128;
    int wr = wid >> 1, wc = wid & 1;
    int fr = l & 15, fk = l >> 4;
    f32x4 acc[4][4] = {};
    constexpr int NCH = (MODE == SPLIT_NONE) ? 16 : 24;   // 1KB chunks per k-tile
    constexpr int PW  = NCH / 4;
    for (int k0 = 0; k0 < K; k0 += 32) {
        __syncthreads();                                  // prior reads done
        #pragma unroll
        for (int i = 0; i < PW; ++i) {
            int cid = wid * PW + i;
            int arr = cid >> 3, ch = cid & 7;
            int kb = ch >> 1, row = (ch & 1) * 64 + l;
            const unsigned short* g; unsigned short* ld;
            if (arr == 0)      { g = A0 + (long)(m0 + row) * K; ld = LA; }
            else if (arr == 1) { g = Bh + (long)(n0 + row) * K; ld = LB; }
            else {
                if (MODE == SPLIT_A) g = A1 + (long)(m0 + row) * K;
                else                 g = B1 + (long)(n0 + row) * K;
                ld = LX;
            }
            __builtin_amdgcn_global_load_lds(
                (const __attribute__((address_space(1))) unsigned int*)(g + k0 + kb * 8),
                (__attribute__((address_space(3))) unsigned int*)(ld + kb * 1024 + (ch & 1) * 512),
                16, 0, 0);
        }
        __syncthreads();                                  // staging landed
        bf16x8 a0[4], b0[4], xf[4];
        #pragma unroll
        for (int t = 0; t < 4; ++t) {
            a0[t] = *(const bf16x8*)&LA[(fk * 128 + wr * 64 + t * 16 + fr) * 8];
            b0[t] = *(const bf16x8*)&LB[(fk * 128 + wc * 64 + t * 16 + fr) * 8];
            if (MODE == SPLIT_A) xf[t] = *(const bf16x8*)&LX[(fk * 128 + wr * 64 + t * 16 + fr) * 8];
            if (MODE == SPLIT_B) xf[t] = *(const bf16x8*)&LX[(fk * 128 + wc * 64 + t * 16 + fr) * 8];
        }
        #pragma unroll
        for (int mt = 0; mt < 4; ++mt)
            #pragma unroll
            for (int nt = 0; nt < 4; ++nt) {
                acc[mt][nt] = __builtin_amdgcn_mfma_f32_16x16x32_bf16(a0[mt], b0[nt], acc[mt][nt], 0, 0, 0);
                if (MODE == SPLIT_A)
                    acc[mt][nt] = __builtin_amdgcn_mfma_f32_16x16x32_bf16(xf[mt], b0[nt], acc[mt][nt], 0, 0, 0);
                if (MODE == SPLIT_B)
                    acc[mt][nt] = __builtin_amdgcn_mfma_f32_16x16x32_bf16(a0[mt], xf[nt], acc[mt][nt], 0, 0, 0);
            }
    }
    int drb = (l >> 4) * 4;
    #pragma unroll
    for (int mt = 0; mt < 4; ++mt)
        #pragma unroll
        for (int nt = 0; nt < 4; ++nt)
            #pragma unroll
            for (int e = 0; e < 4; ++e) {
                int row = m0 + wr * 64 + mt * 16 + drb + e;
                int cc  = n0 + wc * 64 + nt * 16 + (l & 15);
                float v = acc[mt][nt][e];
                if (Wadd) v = fmaf(af[row], Wadd[(long)row * N + cc], v);
                C[(long)row * N + cc] = v;
            }
}

// ---------------- fp64 re-check of near-zero dots (sign safety) --------------------
__global__ __launch_bounds__(256) void k_fixup(const unsigned short* __restrict__ Hh,
        const float* __restrict__ w, float* __restrict__ dots) {
    long i = (long)blockIdx.x * 256 + threadIdx.x;
    float d = dots[i];
    if (fabsf(d) < 1e-3f) {
        int s = (int)(i / CA3C), c = (int)(i % CA3C);
        const unsigned short* hr = Hh + (long)s * NN;
        const float* wr = w + (long)c * NN;
        double acc = 0.0;
        for (int n = 0; n < NN; ++n) acc += (double)bf2f(hr[n]) * (double)wr[n];
        dots[i] = (acc > 0.0) ? 1.0f : -1.0f;   // only the sign is consumed
    }
}

// ---------------- pack: preT[w][s] bits, popf[s], dense Xb bf16 (0/1 exact) --------
__global__ __launch_bounds__(64) void k_pack(const float* __restrict__ dots,
        unsigned* __restrict__ preT, float* __restrict__ popf,
        unsigned short* __restrict__ Xb) {
    int s = blockIdx.x;
    int w = threadIdx.x;
    const float* row = dots + (long)s * CA3C + w * 32;
    unsigned short* xrow = Xb + (long)s * CA3C + w * 32;
    unsigned m = 0;
    #pragma unroll
    for (int j4 = 0; j4 < 8; ++j4) {
        f32x4 v = *(const f32x4*)(row + j4 * 4);
        u16x4 xb;
        xb.x = v.x > 0.f ? 0x3F80 : 0; xb.y = v.y > 0.f ? 0x3F80 : 0;
        xb.z = v.z > 0.f ? 0x3F80 : 0; xb.w = v.w > 0.f ? 0x3F80 : 0;
        m |= (v.x > 0.f ? 1u : 0u) << (j4 * 4 + 0);
        m |= (v.y > 0.f ? 1u : 0u) << (j4 * 4 + 1);
        m |= (v.z > 0.f ? 1u : 0u) << (j4 * 4 + 2);
        m |= (v.w > 0.f ? 1u : 0u) << (j4 * 4 + 3);
        *(u16x4*)(xrow + j4 * 4) = xb;
    }
    preT[w * SEQ + s] = m;
    int pc = __popc(m);
    #pragma unroll
    for (int o = 1; o < 64; o <<= 1) pc += __shfl_xor(pc, o, 64);
    if (w == 0) popf[s] = (float)pc;
}

// ---------------- post bits per row: postT[r][32 words over steps 0..1022] ---------
__global__ __launch_bounds__(256) void k_packpost(const float* __restrict__ dots,
        unsigned* __restrict__ postT) {
    int r = blockIdx.x * 256 + threadIdx.x;    // 0..2047
    #pragma unroll 1
    for (int wi = 0; wi < 32; ++wi) {
        unsigned m = 0;
        int jmax = (wi == 31) ? 31 : 32;       // steps s = wi*32+j, s <= 1022
        for (int j = 0; j < jmax; ++j) {
            int s = wi * 32 + j;
            m |= (dots[(long)(s + 1) * CA3C + r] > 0.0f ? 1u : 0u) << j;
        }
        postT[r * 32 + wi] = m;
    }
}

// ---------------- transpose Xb[s][n] -> XbT[n][s] (bf16) ---------------------------
__global__ __launch_bounds__(256) void k_transpose(const unsigned short* __restrict__ Xb,
        unsigned short* __restrict__ XbT) {
    __shared__ unsigned short t[64][72];
    int s0 = blockIdx.x * 64, n0 = blockIdx.y * 64;
    int tx = threadIdx.x & 63, ty = threadIdx.x >> 6;
    #pragma unroll
    for (int ii = 0; ii < 16; ++ii) {
        int i = ty + ii * 4;
        t[i][tx] = Xb[(long)(s0 + i) * CA3C + n0 + tx];
    }
    __syncthreads();
    #pragma unroll
    for (int ii = 0; ii < 16; ++ii) {
        int i = ty + ii * 4;
        XbT[(long)(n0 + i) * SEQ + s0 + tx] = t[tx][i];
    }
}

// ---------------- Gram matrix G[i][j] = x_i . x_j via popcount (fp32 out) ----------
__global__ __launch_bounds__(256) void k_gram(const unsigned* __restrict__ preT,
        float* __restrict__ G) {
    int i = blockIdx.x;
    int t = threadIdx.x;
    int a0 = 0, a1 = 0, a2 = 0, a3 = 0;
    #pragma unroll 8
    for (int w = 0; w < 64; ++w) {
        unsigned ri = preT[w * SEQ + i];       // uniform -> broadcast
        const unsigned* pr = preT + w * SEQ;
        a0 += __popc(ri & pr[t]);
        a1 += __popc(ri & pr[t + 256]);
        a2 += __popc(ri & pr[t + 512]);
        a3 += __popc(ri & pr[t + 768]);
    }
    long base = (long)i * SEQ;
    G[base + t] = (float)a0;       G[base + t + 256] = (float)a1;
    G[base + t + 512] = (float)a2; G[base + t + 768] = (float)a3;
}

// ---------------- DPP-based full-wave (64 lane) sum; broadcast via lane 63 ---------
__device__ __forceinline__ float wave_sum64(float x) {
    #define DPPADD(ctrl, rmask) \
        x += __int_as_float(__builtin_amdgcn_update_dpp(0, __float_as_int(x), ctrl, rmask, 0xF, true))
    DPPADD(0xB1, 0xF);
    DPPADD(0x4E, 0xF);
    DPPADD(0x141, 0xF);
    DPPADD(0x140, 0xF);
    DPPADD(0x142, 0xA);
    DPPADD(0x143, 0xC);
    #undef DPPADD
    return __int_as_float(__builtin_amdgcn_readlane(__float_as_int(x), 63));
}

// ---------------- Phase D (Gram form): unchanged from R7 ---------------------------
__global__ __launch_bounds__(256) void k_scan2(const float* __restrict__ W0,
        const float* __restrict__ B0, const float* __restrict__ G,
        const unsigned* __restrict__ postT, const float* __restrict__ popf,
        float* __restrict__ coef, float* __restrict__ alphaf) {
    __shared__ float Gd[64][68];
    __shared__ float ctab[4][1024];
    int wid = threadIdx.x >> 6, lane = threadIdx.x & 63;
    int r = blockIdx.x * 4 + wid;
    #pragma unroll
    for (int kk = 0; kk < 16; ++kk) ctab[wid][kk * 64 + lane] = 0.f;
    const float* wr = W0 + (long)r * NN + lane * 32;
    f32x4 q0 = *(const f32x4*)(wr +  0), q1 = *(const f32x4*)(wr +  4);
    f32x4 q2 = *(const f32x4*)(wr +  8), q3 = *(const f32x4*)(wr + 12);
    f32x4 q4 = *(const f32x4*)(wr + 16), q5 = *(const f32x4*)(wr + 20);
    f32x4 q6 = *(const f32x4*)(wr + 24), q7 = *(const f32x4*)(wr + 28);
    f32x4 pp = q0*q0 + q1*q1 + q2*q2 + q3*q3 + q4*q4 + q5*q5 + q6*q6 + q7*q7;
    float nu = wave_sum64((pp.x + pp.y) + (pp.z + pp.w));
    float alpha = 1.f, inv_alpha = 1.f;
    { float t = fmaxf(nu, 1.f); alpha *= rsqrtf(t); inv_alpha *= sqrtf(t); nu = fminf(nu, 1.f); }
    float s0 = 1.f;

    for (int b = 0; b < 16; ++b) {
        __syncthreads();
        {
            int gi = threadIdx.x >> 2, gj = (threadIdx.x & 3) * 16;
            const float* gs = G + (long)(b * 64 + gi) * SEQ + b * 64 + gj;
            *(f32x4*)&Gd[gi][gj +  0] = *(const f32x4*)(gs +  0);
            *(f32x4*)&Gd[gi][gj +  4] = *(const f32x4*)(gs +  4);
            *(f32x4*)&Gd[gi][gj +  8] = *(const f32x4*)(gs +  8);
            *(f32x4*)&Gd[gi][gj + 12] = *(const f32x4*)(gs + 12);
        }
        __syncthreads();
        float myB0  = B0[(long)r * SEQ + b * 64 + lane];
        float mypop = popf[b * 64 + lane];
        unsigned long long pm;
        {   unsigned lo = postT[r * 32 + 2 * b], hi = postT[r * 32 + 2 * b + 1];
            pm = ((unsigned long long)(unsigned)__builtin_amdgcn_readfirstlane((int)hi) << 32)
               |  (unsigned long long)(unsigned)__builtin_amdgcn_readfirstlane((int)lo);
        }
        float ib0 = 0.f, ib1 = 0.f, ib2 = 0.f, ib3 = 0.f;
        const float* gcol = G + (long)b * 64 + lane;
        #pragma unroll 2
        for (int sp = 0; sp < b * 64; sp += 4) {
            f32x4 cq = *(const f32x4*)&ctab[wid][sp];
            ib0 = fmaf(cq.x, gcol[(long)(sp + 0) * SEQ], ib0);
            ib1 = fmaf(cq.y, gcol[(long)(sp + 1) * SEQ], ib1);
            ib2 = fmaf(cq.z, gcol[(long)(sp + 2) * SEQ], ib2);
            ib3 = fmaf(cq.w, gcol[(long)(sp + 3) * SEQ], ib3);
        }
        float acc = fmaf(s0, myB0, (ib0 + ib1) + (ib2 + ib3));
        float cj = 0.f;
        #pragma unroll
        for (int j = 0; j < 64; ++j) {
            if ((pm >> j) & 1ull) {
                float dot = __int_as_float(__builtin_amdgcn_readlane(__float_as_int(acc), j));
                float pj  = __int_as_float(__builtin_amdgcn_readlane(__float_as_int(mypop), j));
                float c = LRC * inv_alpha;
                nu = fmaf(2.f * LRC, alpha * dot, fmaf(LRC * LRC, pj, nu));
                float t = fmaxf(nu, 1.f);
                alpha *= rsqrtf(t); inv_alpha *= sqrtf(t); nu = fminf(nu, 1.f);
                acc = fmaf(c, Gd[j][lane], acc);
                cj = (lane == j) ? c : cj;
            }
        }
        ctab[wid][b * 64 + lane] = cj;
        if (inv_alpha > 1e10f) {
            #pragma unroll 1
            for (int kk = 0; kk <= b; ++kk) ctab[wid][kk * 64 + lane] *= alpha;
            s0 *= alpha; alpha = 1.f; inv_alpha = 1.f;
        }
    }
    if (lane == 0) alphaf[r] = alpha * s0;
    #pragma unroll
    for (int kk = 0; kk < 16; ++kk)
        coef[(long)r * SEQ + kk * 64 + lane] = alpha * ctab[wid][kk * 64 + lane];
}

extern "C" void kernel_launch(void* const* d_in, const int* in_sizes, int n_in,
                              void* d_out, int out_size, void* d_ws, size_t ws_size,
                              hipStream_t stream) {
    const int*   tok     = (const int*)d_in[0];
    const float* sdr     = (const float*)d_in[1];
    const float* pos     = (const float*)d_in[2];
    const float* w_hippo = (const float*)d_in[3];
    const float* assoc   = (const float*)d_in[4];
    float* out = (float*)d_out;

    char* ws = (char*)d_ws;
    // Slot map (36.6 MB total, aliased by lifetime):
    unsigned short* Hh  = (unsigned short*)(ws);                 // 0-4 MB (dead after fixup)
    float*          G   = (float*)(ws);                          //   then G (gram, 4 MB)
    unsigned short* Wh  = (unsigned short*)(ws + (4l << 20));    // 4-12 MB (dead after dots)
    unsigned short* Sh  = Wh;                                    //   then assoc-bf16
    unsigned short* Ch  = Wh;                                    //   then coef-hi (4 MB)
    unsigned short* Cl  = (unsigned short*)(ws + (8l << 20));    //   coef-lo   (4 MB)
    unsigned short* Wl  = (unsigned short*)(ws + (12l << 20));   // 12-20 MB (dead after dots)
    float*          coef= (float*)(ws + (12l << 20));            //   then coef fp32 (8 MB)
    float*          dots= (float*)(ws + (20l << 20));            // 20-28 MB (dead after pack)
    float*          B0f = dots;                                  //   then B0 (8 MB)
    unsigned short* Xb  = (unsigned short*)(ws + (28l << 20));   // 28-32 MB
    unsigned short* XbT = (unsigned short*)(ws + (32l << 20));   // 32-36 MB
    unsigned* preT   = (unsigned*)(ws + (36l << 20));            // 256 KB
    unsigned* postT  = (unsigned*)(ws + (36l << 20) + 262144);   // 256 KB
    float*    popf   = (float*)(ws + (36l << 20) + 524288);      // 4 KB
    float*    alphaf = (float*)(ws + (36l << 20) + 532480);      // 8 KB

    k_hippo            <<<dim3(SEQ, 2),   256, 0, stream>>>(tok, sdr, pos, Hh);
    k_split            <<<2048,           256, 0, stream>>>(w_hippo, Wh, Wl);
    k_mgemm<SPLIT_B>   <<<dim3(16, 8),    256, 0, stream>>>(Hh, nullptr, Wh, Wl, dots,
                                                            1024, 2048, 2048, nullptr, nullptr);
    k_fixup            <<<8192,           256, 0, stream>>>(Hh, w_hippo, dots);
    k_pack             <<<SEQ,             64, 0, stream>>>(dots, preT, popf, Xb);
    k_packpost         <<<8,              256, 0, stream>>>(dots, postT);
    k_transpose        <<<dim3(16, 32),   256, 0, stream>>>(Xb, XbT);
    k_gram             <<<SEQ,            256, 0, stream>>>(preT, G);
    k_split            <<<2048,           256, 0, stream>>>(assoc, Sh, nullptr);
    k_mgemm<SPLIT_NONE><<<dim3(8, 16),    256, 0, stream>>>(Sh, nullptr, Xb, nullptr, B0f,
                                                            2048, 1024, 2048, nullptr, nullptr);
    k_scan2            <<<512,            256, 0, stream>>>(assoc, B0f, G, postT, popf, coef, alphaf);
    k_split            <<<1024,           256, 0, stream>>>(coef, Ch, Cl);
    k_mgemm<SPLIT_A>   <<<dim3(16, 16),   256, 0, stream>>>(Ch, Cl, XbT, nullptr, out,
                                                            2048, 2048, 1024, assoc, alphaf);
}